// Round 6
// baseline (297.745 us; speedup 1.0000x reference)
//
#include <hip/hip_runtime.h>

typedef _Float16 f16x8 __attribute__((ext_vector_type(8)));
typedef unsigned short u16x8v __attribute__((ext_vector_type(8)));
typedef unsigned short u16x4v __attribute__((ext_vector_type(4)));
typedef float f32x4 __attribute__((ext_vector_type(4)));

constexpr int SEQ = 2048;
constexpr int DIM = 1024;
constexpr int BATCH = 4;
constexpr size_t NBS = (size_t)BATCH * SEQ * DIM;  // 8388608

static __device__ __forceinline__ unsigned short f2h(float f) {
    return __builtin_bit_cast(unsigned short, (_Float16)f);  // RNE
}
static __device__ __forceinline__ float h2f(unsigned short u) {
    return (float)__builtin_bit_cast(_Float16, u);
}
static __device__ __forceinline__ f16x8 ldsld(const unsigned short* p) {
    return __builtin_bit_cast(f16x8, *(const u16x8v*)p);
}
// Async global->LDS, 16B/lane. LDS dest = wave-uniform base + lane*16B.
static __device__ __forceinline__ void gld_lds16(const unsigned short* g, unsigned short* l) {
    __builtin_amdgcn_global_load_lds(
        (const __attribute__((address_space(1))) void*)g,
        (__attribute__((address_space(3))) void*)l, 16, 0, 0);
}

// ---------------------------------------------------------------------------
// cvt + Mt kernel, ONE launch, three block classes:
//   [0,64):            Mt = Wq^T*Wk fold: Mt[e'][e] = sum_k Wq[k][e]*Wk[k][e']
//                      (fp32 inputs read directly; in-LDS transpose with 16B-
//                      unit rotation; MFMA fp16). Dispatched FIRST so the ~6 us
//                      of matrix work hides under the cvt memory traffic.
//   [64, 64+8192):     X fp32 -> fp16.
//   [64+8192, +1024):  Wv fp32 -> fp16.
// ---------------------------------------------------------------------------
__global__ __launch_bounds__(256) void cvt_mt(
    const float* __restrict__ X,
    const float* __restrict__ Wq32, const float* __restrict__ Wk32,
    const float* __restrict__ Wv32,
    unsigned short* __restrict__ Xf, unsigned short* __restrict__ Wvf,
    unsigned short* __restrict__ Mt)
{
    __shared__ __attribute__((aligned(16))) unsigned short LA[128 * 64];  // WkT tile [e'][k]
    __shared__ __attribute__((aligned(16))) unsigned short LB[128 * 64];  // WqT tile [e][k]
    const int b = blockIdx.x;
    const int tid = threadIdx.x;

    if (b >= 64) {
        // ------- plain cvt blocks -------
        const float* src;
        unsigned short* dst;
        int i;
        const int cb = b - 64;
        if (cb < 8192) {
            src = X; dst = Xf;
            i = cb * 256 + tid;
        } else {
            src = Wv32; dst = Wvf;
            i = (cb - 8192) * 256 + tid;
        }
        float4 f = ((const float4*)src)[i];
        u16x4v h;
        h.x = f2h(f.x); h.y = f2h(f.y); h.z = f2h(f.z); h.w = f2h(f.w);
        ((u16x4v*)dst)[i] = h;
        return;
    }

    // ------- Mt blocks -------
    const int e0p = (b >> 3) * 128;   // e' rows (from Wk)
    const int e0  = (b & 7) * 128;    // e  cols (from Wq)
    const int w = tid >> 6, lane = tid & 63, q = lane >> 4, c = lane & 15;
    const int wrow = (w >> 1) * 64, wcol = (w & 1) * 64;
    const int kr = tid >> 5;          // 0..7  (k within 8-row group)
    const int ec = (tid & 31) * 4;    // 0..124 (e base, 4 per thread)

    f32x4 acc[4][4];
#pragma unroll
    for (int a = 0; a < 4; ++a)
#pragma unroll
        for (int bq = 0; bq < 4; ++bq) acc[a][bq] = (f32x4){0.f, 0.f, 0.f, 0.f};

    for (int k0 = 0; k0 < DIM; k0 += 64) {
        __syncthreads();
#pragma unroll
        for (int s = 0; s < 8; ++s) {
            const int k = k0 + kr + 8 * s;          // global k row
            float4 av = *(const float4*)(Wk32 + (size_t)k * DIM + e0p + ec);
            float4 bv = *(const float4*)(Wq32 + (size_t)k * DIM + e0 + ec);
            // element (e_local, klocal): klocal = kr + 8s -> unit s, slot kr.
#pragma unroll
            for (int i = 0; i < 4; ++i) {
                const int ea = ec + i;
                const int off = ea * 64 + (((s + ea) & 7) << 3) + kr;
                LA[off] = f2h(((const float*)&av)[i]);
                LB[off] = f2h(((const float*)&bv)[i]);
            }
        }
        __syncthreads();
#pragma unroll
        for (int kk = 0; kk < 2; ++kk) {
            f16x8 af[4], bf[4];
#pragma unroll
            for (int mi = 0; mi < 4; ++mi) {
                const int ep = wrow + mi * 16 + c;
                af[mi] = ldsld(LA + ep * 64 + (((((kk << 2) + q) + ep) & 7) << 3));
            }
#pragma unroll
            for (int ni = 0; ni < 4; ++ni) {
                const int ee = wcol + ni * 16 + c;
                bf[ni] = ldsld(LB + ee * 64 + (((((kk << 2) + q) + ee) & 7) << 3));
            }
#pragma unroll
            for (int mi = 0; mi < 4; ++mi)
#pragma unroll
                for (int ni = 0; ni < 4; ++ni)
                    acc[mi][ni] = __builtin_amdgcn_mfma_f32_16x16x32_f16(af[mi], bf[ni], acc[mi][ni], 0, 0, 0);
        }
    }
#pragma unroll
    for (int mi = 0; mi < 4; ++mi)
#pragma unroll
        for (int ni = 0; ni < 4; ++ni) {
            const int col = e0 + wcol + ni * 16 + c;
#pragma unroll
            for (int r = 0; r < 4; ++r) {
                const int row = e0p + wrow + mi * 16 + q * 4 + r;
                Mt[(size_t)row * DIM + col] = f2h(acc[mi][ni][r]);
            }
        }
}

// ---------------------------------------------------------------------------
// Fused Y/V projection, fp16 MFMA. z=0: Y = NT(Xf, Mt) (scores operand,
// replaces BOTH Q and K projections via scores = X*M*X^T); z=1: V = NT(Xf,
// Wvf), stored transposed Vt[b][d][s]. 128x128 tile, 4 waves x 64x64, BK=64,
// XOR-swizzled LDS (linear gld_lds dest + inverse-swizzled global source +
// swizzled read). 2-D grid, m fastest (keeps 256 KB B-panel L2-hot).
// ---------------------------------------------------------------------------
__global__ __launch_bounds__(256) void yv_gemm(
    const unsigned short* __restrict__ Xf, const unsigned short* __restrict__ Mt,
    const unsigned short* __restrict__ Wvf,
    unsigned short* __restrict__ Yf, unsigned short* __restrict__ Vt)
{
    __shared__ __attribute__((aligned(16))) unsigned short Ah[128 * 64];
    __shared__ __attribute__((aligned(16))) unsigned short Bh[128 * 64];
    const int m0 = blockIdx.x * 128, n0 = blockIdx.y * 128, z = blockIdx.z;
    const unsigned short* Wz = z ? Wvf : Mt;
    const int tid = threadIdx.x;
    const int w = tid >> 6, lane = tid & 63, q = lane >> 4, c = lane & 15;
    const int wrow = (w >> 1) * 64, wcol = (w & 1) * 64;
    const int g8 = lane >> 3;                 // row-in-group 0..7
    const int cu = (lane & 7) ^ g8;           // inverse-swizzled col unit
    const int srow = w * 8 + g8;              // staging row (call j adds j*32)
    const int scol = cu * 8;                  // shorts
    unsigned short* lA = Ah + w * 512;        // wave-uniform LDS bases
    unsigned short* lB = Bh + w * 512;
    const int c7 = c & 7;

    f32x4 acc[4][4];
#pragma unroll
    for (int a = 0; a < 4; ++a)
#pragma unroll
        for (int b = 0; b < 4; ++b) acc[a][b] = (f32x4){0.f, 0.f, 0.f, 0.f};

    for (int k0 = 0; k0 < DIM; k0 += 64) {
        __syncthreads();
        {
            const size_t ga = (size_t)(m0 + srow) * DIM + k0 + scol;
            const size_t gb = (size_t)(n0 + srow) * DIM + k0 + scol;
#pragma unroll
            for (int j = 0; j < 4; ++j) {
                gld_lds16(Xf + ga + (size_t)(j * 32) * DIM, lA + j * 2048);
                gld_lds16(Wz + gb + (size_t)(j * 32) * DIM, lB + j * 2048);
            }
        }
        __syncthreads();
#pragma unroll
        for (int kk = 0; kk < 2; ++kk) {
            f16x8 ah[4], bh[4];
#pragma unroll
            for (int mi = 0; mi < 4; ++mi)
                ah[mi] = ldsld(Ah + (wrow + mi * 16 + c) * 64 + (((kk << 2) + q) ^ c7) * 8);
#pragma unroll
            for (int ni = 0; ni < 4; ++ni)
                bh[ni] = ldsld(Bh + (wcol + ni * 16 + c) * 64 + (((kk << 2) + q) ^ c7) * 8);
#pragma unroll
            for (int mi = 0; mi < 4; ++mi)
#pragma unroll
                for (int ni = 0; ni < 4; ++ni)
                    acc[mi][ni] = __builtin_amdgcn_mfma_f32_16x16x32_f16(ah[mi], bh[ni], acc[mi][ni], 0, 0, 0);
        }
    }

    if (z == 1) {
        // V: store transposed Vt[b][d][s], fp16.
#pragma unroll
        for (int mi = 0; mi < 4; ++mi) {
            const int mg = m0 + wrow + mi * 16 + q * 4;
            const int bb = mg >> 11, ss = mg & (SEQ - 1);
#pragma unroll
            for (int ni = 0; ni < 4; ++ni) {
                const int col = n0 + wcol + ni * 16 + c;
                u16x4v v;
                v.x = f2h(acc[mi][ni][0]);
                v.y = f2h(acc[mi][ni][1]);
                v.z = f2h(acc[mi][ni][2]);
                v.w = f2h(acc[mi][ni][3]);
                *(u16x4v*)(Vt + ((size_t)bb * DIM + col) * SEQ + ss) = v;
            }
        }
    } else {
#pragma unroll
        for (int mi = 0; mi < 4; ++mi)
#pragma unroll
            for (int ni = 0; ni < 4; ++ni) {
                const int col = n0 + wcol + ni * 16 + c;
#pragma unroll
                for (int r = 0; r < 4; ++r) {
                    const int row = m0 + wrow + mi * 16 + q * 4 + r;
                    Yf[(size_t)row * DIM + col] = f2h(acc[mi][ni][r]);
                }
            }
    }
}

// ---------------------------------------------------------------------------
// Scores GEMM, ALL batches: S = Yf Xf^T * SCALE (== Q K^T), fp16 out.
// Faithful masking of scores==0 on the f32 accumulator: writes 0xFC00.
// Triangular-flattened grid: x = t in [0,136). BK=64 swizzled.
// ---------------------------------------------------------------------------
__global__ __launch_bounds__(256) void scores_gemm1b(
    const unsigned short* __restrict__ Q, const unsigned short* __restrict__ K,
    unsigned short* __restrict__ S)
{
    __shared__ __attribute__((aligned(16))) unsigned short Ah[128 * 64];
    __shared__ __attribute__((aligned(16))) unsigned short Bh[128 * 64];
    const int t = blockIdx.x;                  // 0..135
    int ti = (int)((__builtin_sqrtf(8.f * t + 1.f) - 1.f) * 0.5f);
    while ((ti + 1) * (ti + 2) / 2 <= t) ++ti;
    while (ti * (ti + 1) / 2 > t) --ti;
    const int tj = t - ti * (ti + 1) / 2;
    const int i0 = ti * 128, j0 = tj * 128, b = blockIdx.z;
    const unsigned short* Qb = Q + (size_t)b * SEQ * DIM;
    const unsigned short* Kb = K + (size_t)b * SEQ * DIM;
    unsigned short* Sb = S + (size_t)b * SEQ * SEQ;
    const int tid = threadIdx.x;
    const int w = tid >> 6, lane = tid & 63, q = lane >> 4, c = lane & 15;
    const int wrow = (w >> 1) * 64, wcol = (w & 1) * 64;
    const int g8 = lane >> 3;
    const int cu = (lane & 7) ^ g8;
    const int srow = w * 8 + g8;
    const int scol = cu * 8;
    unsigned short* lA = Ah + w * 512;
    unsigned short* lB = Bh + w * 512;
    const int c7 = c & 7;

    f32x4 acc[4][4];
#pragma unroll
    for (int a = 0; a < 4; ++a)
#pragma unroll
        for (int bq = 0; bq < 4; ++bq) acc[a][bq] = (f32x4){0.f, 0.f, 0.f, 0.f};

    for (int k0 = 0; k0 < DIM; k0 += 64) {
        __syncthreads();
        {
            const size_t ga = (size_t)(i0 + srow) * DIM + k0 + scol;
            const size_t gb = (size_t)(j0 + srow) * DIM + k0 + scol;
#pragma unroll
            for (int j = 0; j < 4; ++j) {
                gld_lds16(Qb + ga + (size_t)(j * 32) * DIM, lA + j * 2048);
                gld_lds16(Kb + gb + (size_t)(j * 32) * DIM, lB + j * 2048);
            }
        }
        __syncthreads();
#pragma unroll
        for (int kk = 0; kk < 2; ++kk) {
            f16x8 ah[4], bh[4];
#pragma unroll
            for (int mi = 0; mi < 4; ++mi)
                ah[mi] = ldsld(Ah + (wrow + mi * 16 + c) * 64 + (((kk << 2) + q) ^ c7) * 8);
#pragma unroll
            for (int ni = 0; ni < 4; ++ni)
                bh[ni] = ldsld(Bh + (wcol + ni * 16 + c) * 64 + (((kk << 2) + q) ^ c7) * 8);
#pragma unroll
            for (int mi = 0; mi < 4; ++mi)
#pragma unroll
                for (int ni = 0; ni < 4; ++ni)
                    acc[mi][ni] = __builtin_amdgcn_mfma_f32_16x16x32_f16(ah[mi], bh[ni], acc[mi][ni], 0, 0, 0);
        }
    }
#pragma unroll
    for (int mi = 0; mi < 4; ++mi)
#pragma unroll
        for (int ni = 0; ni < 4; ++ni) {
            const int col = j0 + wcol + ni * 16 + c;
#pragma unroll
            for (int r = 0; r < 4; ++r) {
                const int row = i0 + wrow + mi * 16 + q * 4 + r;
                const float sc = acc[mi][ni][r] * 0.03125f;
                Sb[(size_t)row * SEQ + col] =
                    (sc == 0.f) ? (unsigned short)0xFC00u : f2h(sc);
            }
        }
}

// ---------------------------------------------------------------------------
// Row-wise masked softmax: fp16 S -> fp16 P. j > i masked; scores==0 already
// -inf. Skip loads beyond i, skip writes beyond rowtile end. Grid (SEQ, BATCH).
// ---------------------------------------------------------------------------
__global__ __launch_bounds__(256) void softmax_row_b(
    const unsigned short* __restrict__ S, unsigned short* __restrict__ P)
{
    const int i = blockIdx.x, t = threadIdx.x;
    const size_t ro = ((size_t)blockIdx.y * SEQ + i) * SEQ;
    const int wid = t >> 6, lane = t & 63;
    __shared__ float redm[4], reds[4];
    const int j0 = t * 8;
    const int rti = (i & ~127) + 128;        // pv reads cols < rti only
    float sv[8];
    float mx = -__builtin_inff();
    if (j0 <= i) {
        u16x8v raw = *(const u16x8v*)(S + ro + j0);
#pragma unroll
        for (int u = 0; u < 8; ++u) {
            float s = (j0 + u <= i) ? h2f(raw[u]) : -__builtin_inff();
            sv[u] = s;
            mx = fmaxf(mx, s);
        }
    } else {
#pragma unroll
        for (int u = 0; u < 8; ++u) sv[u] = -__builtin_inff();
    }
#pragma unroll
    for (int off = 1; off < 64; off <<= 1) mx = fmaxf(mx, __shfl_xor(mx, off));
    if (lane == 0) redm[wid] = mx;
    __syncthreads();
    const float M = fmaxf(fmaxf(redm[0], redm[1]), fmaxf(redm[2], redm[3]));
    float sum = 0.f;
#pragma unroll
    for (int u = 0; u < 8; ++u) {
        float e = __expf(sv[u] - M);
        sv[u] = e;
        sum += e;
    }
#pragma unroll
    for (int off = 1; off < 64; off <<= 1) sum += __shfl_xor(sum, off);
    if (lane == 0) reds[wid] = sum;
    __syncthreads();
    const float rinv = 1.f / (reds[0] + reds[1] + reds[2] + reds[3]);
    if (j0 < rti) {
        u16x8v o;
#pragma unroll
        for (int u = 0; u < 8; ++u) o[u] = f2h(sv[u] * rinv);
        *(u16x8v*)(P + ro + j0) = o;
    }
}

// ---------------------------------------------------------------------------
// out = P @ V via Vt (NT MFMA, fp16), fp32 store. 128x128 tile, BK=64
// swizzled; k-loop truncated at causal bound. Long/short tiles interleaved
// across batch halves (neutral-but-kept from r5).
// ---------------------------------------------------------------------------
__global__ __launch_bounds__(256) void pv_gemm(
    const unsigned short* __restrict__ Pm, const unsigned short* __restrict__ Vt,
    float* __restrict__ Out)
{
    __shared__ __attribute__((aligned(16))) unsigned short Ps[128 * 64];
    __shared__ __attribute__((aligned(16))) unsigned short Vs[128 * 64];
    const int b = blockIdx.z;
    const int i0t = (b < 2) ? blockIdx.x : 15 - blockIdx.x;
    const int i0 = i0t * 128, d0 = blockIdx.y * 128;
    const int tid = threadIdx.x;
    const int w = tid >> 6, lane = tid & 63, q = lane >> 4, c = lane & 15;
    const int wrow = (w >> 1) * 64, wcol = (w & 1) * 64;
    const int g8 = lane >> 3;
    const int cu = (lane & 7) ^ g8;
    const int srow = w * 8 + g8;
    const int scol = cu * 8;
    unsigned short* lA = Ps + w * 512;
    unsigned short* lB = Vs + w * 512;
    const int c7 = c & 7;

    f32x4 acc[4][4];
#pragma unroll
    for (int a = 0; a < 4; ++a)
#pragma unroll
        for (int bq = 0; bq < 4; ++bq) acc[a][bq] = (f32x4){0.f, 0.f, 0.f, 0.f};

    const int njs = 2 * i0t + 2;  // covers cols < i0+128

    for (int ks = 0; ks < njs; ++ks) {
        const int j0 = ks * 64;
        __syncthreads();
        {
            const size_t gpa = ((size_t)b * SEQ + i0 + srow) * SEQ + j0 + scol;
            const size_t gva = ((size_t)b * DIM + d0 + srow) * SEQ + j0 + scol;
#pragma unroll
            for (int j = 0; j < 4; ++j) {
                gld_lds16(Pm + gpa + (size_t)(j * 32) * SEQ, lA + j * 2048);
                gld_lds16(Vt + gva + (size_t)(j * 32) * SEQ, lB + j * 2048);
            }
        }
        __syncthreads();
#pragma unroll
        for (int kk = 0; kk < 2; ++kk) {
            f16x8 ah[4], bh[4];
#pragma unroll
            for (int mi = 0; mi < 4; ++mi)
                ah[mi] = ldsld(Ps + (wrow + mi * 16 + c) * 64 + (((kk << 2) + q) ^ c7) * 8);
#pragma unroll
            for (int ni = 0; ni < 4; ++ni)
                bh[ni] = ldsld(Vs + (wcol + ni * 16 + c) * 64 + (((kk << 2) + q) ^ c7) * 8);
#pragma unroll
            for (int mi = 0; mi < 4; ++mi)
#pragma unroll
                for (int ni = 0; ni < 4; ++ni)
                    acc[mi][ni] = __builtin_amdgcn_mfma_f32_16x16x32_f16(ah[mi], bh[ni], acc[mi][ni], 0, 0, 0);
        }
    }
#pragma unroll
    for (int mi = 0; mi < 4; ++mi)
#pragma unroll
        for (int ni = 0; ni < 4; ++ni) {
            const int dcol = d0 + wcol + ni * 16 + c;
#pragma unroll
            for (int r = 0; r < 4; ++r) {
                const int i = i0 + wrow + mi * 16 + q * 4 + r;
                Out[((size_t)b * SEQ + i) * DIM + dcol] = acc[mi][ni][r];
            }
        }
}

extern "C" void kernel_launch(void* const* d_in, const int* in_sizes, int n_in,
                              void* d_out, int out_size, void* d_ws, size_t ws_size,
                              hipStream_t stream)
{
    (void)out_size; (void)ws_size;
    const float* X = nullptr;
    const float* Wv[3] = {nullptr, nullptr, nullptr};
    int nw = 0;
    for (int i = 0; i < n_in; ++i) {
        if (in_sizes[i] == (int)NBS)
            X = (const float*)d_in[i];
        else if (nw < 3)
            Wv[nw++] = (const float*)d_in[i];
    }

    unsigned short* ws = (unsigned short*)d_ws;
    unsigned short* Yf = ws;                 // 16 MB (ex-Qf slot)
    unsigned short* Vt = ws + 2 * NBS;       // 16 MB
    unsigned short* Xf = ws + 3 * NBS;       // consumed by yv + scores
    unsigned short* Pp = ws + 3 * NBS;       // P aliases Xf after scores (32 MB)
    unsigned short* Sb = ws + 5 * NBS;       // fp16 S, all batches (32 MB)
    unsigned short* Wvf = ws + 7 * NBS;      // 2 MB
    unsigned short* Mtb = Wvf + (size_t)DIM * DIM;  // 2 MB
    float* Out = (float*)d_out;

    // Wv[0]=WQ, Wv[1]=WK, Wv[2]=WV (input order).
    cvt_mt<<<dim3(64 + 8192 + 1024), 256, 0, stream>>>(
        X, Wv[0], Wv[1], Wv[2], Xf, Wvf, Mtb);

    yv_gemm<<<dim3(64, 8, 2), 256, 0, stream>>>(Xf, Mtb, Wvf, Yf, Vt);

    scores_gemm1b<<<dim3(136, 1, BATCH), 256, 0, stream>>>(Yf, Xf, Sb);
    softmax_row_b<<<dim3(SEQ, BATCH), 256, 0, stream>>>(Sb, Pp);

    pv_gemm<<<dim3(16, 8, BATCH), 256, 0, stream>>>(Pp, Vt, Out);
}

// Round 7
// 259.146 us; speedup vs baseline: 1.1489x; 1.1489x over previous
//
#include <hip/hip_runtime.h>

typedef _Float16 f16x8 __attribute__((ext_vector_type(8)));
typedef unsigned short u16x8v __attribute__((ext_vector_type(8)));
typedef unsigned short u16x4v __attribute__((ext_vector_type(4)));
typedef float f32x4 __attribute__((ext_vector_type(4)));

constexpr int SEQ = 2048;
constexpr int DIM = 1024;
constexpr int BATCH = 4;
constexpr size_t NBS = (size_t)BATCH * SEQ * DIM;  // 8388608

static __device__ __forceinline__ unsigned short f2h(float f) {
    return __builtin_bit_cast(unsigned short, (_Float16)f);  // RNE
}
static __device__ __forceinline__ float h2f(unsigned short u) {
    return (float)__builtin_bit_cast(_Float16, u);
}
static __device__ __forceinline__ f16x8 ldsld(const unsigned short* p) {
    return __builtin_bit_cast(f16x8, *(const u16x8v*)p);
}
// Async global->LDS, 16B/lane. LDS dest = wave-uniform base + lane*16B.
static __device__ __forceinline__ void gld_lds16(const unsigned short* g, unsigned short* l) {
    __builtin_amdgcn_global_load_lds(
        (const __attribute__((address_space(1))) void*)g,
        (__attribute__((address_space(3))) void*)l, 16, 0, 0);
}

// ---------------------------------------------------------------------------
// fp32 -> fp16 convert, X + all 3 W in ONE launch.
// Blocks [0,8192): X. Blocks [8192, 8192+3072): Wq,Wk,Wv.
// ---------------------------------------------------------------------------
__global__ __launch_bounds__(256) void cvt_all(
    const float* __restrict__ X,
    const float* __restrict__ W0, const float* __restrict__ W1,
    const float* __restrict__ W2,
    unsigned short* __restrict__ Xf, unsigned short* __restrict__ Wf)
{
    const int b = blockIdx.x;
    const float* src;
    unsigned short* dst;
    int i;
    if (b < 8192) {
        src = X; dst = Xf;
        i = b * 256 + threadIdx.x;
    } else {
        const int wb = b - 8192;
        const int z = wb >> 10;              // 1024 blocks per weight
        src = (z == 0) ? W0 : (z == 1) ? W1 : W2;
        dst = Wf + (size_t)z * DIM * DIM;
        i = (wb & 1023) * 256 + threadIdx.x;
    }
    float4 f = ((const float4*)src)[i];
    u16x4v h;
    h.x = f2h(f.x); h.y = f2h(f.y); h.z = f2h(f.z); h.w = f2h(f.w);
    ((u16x4v*)dst)[i] = h;
}

// ---------------------------------------------------------------------------
// Mt[e'][e] = sum_k Wq[k][e] * Wk[k][e']   (fp16 in/out, 1024^3).
// TN GEMM done with LINEAR k-major LDS tiles staged by gld_lds16 (coalesced,
// no pre-transpose); the transpose happens at fragment-read time via 8 scalar
// ds_read_u16 per fragment (<=8-way bank conflicts -- acceptable: 2.1 GFLOP
// total). Grid (8,8), 64 blocks, BK=64. r6's fused in-LDS transpose had
// 32-way WRITE conflicts (90 us) -- this replaces it.
// ---------------------------------------------------------------------------
__global__ __launch_bounds__(256) void mt_gemm(
    const unsigned short* __restrict__ Wqf, const unsigned short* __restrict__ Wkf,
    unsigned short* __restrict__ Mt)
{
    __shared__ __attribute__((aligned(16))) unsigned short As[64 * 128];  // Wk [k][e']
    __shared__ __attribute__((aligned(16))) unsigned short Bs[64 * 128];  // Wq [k][e]
    const int e0p = blockIdx.x * 128;   // output rows (from Wk)
    const int e0  = blockIdx.y * 128;   // output cols (from Wq)
    const int tid = threadIdx.x;
    const int w = tid >> 6, lane = tid & 63, q = lane >> 4, c = lane & 15;
    const int wrow = (w >> 1) * 64, wcol = (w & 1) * 64;
    const int kr = lane >> 4;           // 0..3 (row within one 4-row call)
    const int un = lane & 15;           // 16B unit within row

    f32x4 acc[4][4];
#pragma unroll
    for (int a = 0; a < 4; ++a)
#pragma unroll
        for (int b = 0; b < 4; ++b) acc[a][b] = (f32x4){0.f, 0.f, 0.f, 0.f};

    for (int k0 = 0; k0 < DIM; k0 += 64) {
        __syncthreads();
        // Wave w stages k-rows [w*16, w*16+16): 4 calls x 4 rows x 256B.
#pragma unroll
        for (int j = 0; j < 4; ++j) {
            const size_t ga = (size_t)(k0 + w * 16 + j * 4 + kr) * DIM;
            unsigned short* la = As + (w * 16 + j * 4) * 128;
            unsigned short* lb = Bs + (w * 16 + j * 4) * 128;
            gld_lds16(Wkf + ga + e0p + un * 8, la);
            gld_lds16(Wqf + ga + e0  + un * 8, lb);
        }
        __syncthreads();
#pragma unroll
        for (int kk = 0; kk < 2; ++kk) {
            f16x8 af[4], bf[4];
#pragma unroll
            for (int mi = 0; mi < 4; ++mi) {
                u16x8v t_;
#pragma unroll
                for (int j = 0; j < 8; ++j)
                    t_[j] = As[(kk * 32 + q * 8 + j) * 128 + wrow + mi * 16 + c];
                af[mi] = __builtin_bit_cast(f16x8, t_);
            }
#pragma unroll
            for (int ni = 0; ni < 4; ++ni) {
                u16x8v t_;
#pragma unroll
                for (int j = 0; j < 8; ++j)
                    t_[j] = Bs[(kk * 32 + q * 8 + j) * 128 + wcol + ni * 16 + c];
                bf[ni] = __builtin_bit_cast(f16x8, t_);
            }
#pragma unroll
            for (int mi = 0; mi < 4; ++mi)
#pragma unroll
                for (int ni = 0; ni < 4; ++ni)
                    acc[mi][ni] = __builtin_amdgcn_mfma_f32_16x16x32_f16(af[mi], bf[ni], acc[mi][ni], 0, 0, 0);
        }
    }
#pragma unroll
    for (int mi = 0; mi < 4; ++mi)
#pragma unroll
        for (int ni = 0; ni < 4; ++ni) {
            const int col = e0 + wcol + ni * 16 + c;
#pragma unroll
            for (int r = 0; r < 4; ++r) {
                const int row = e0p + wrow + mi * 16 + q * 4 + r;
                Mt[(size_t)row * DIM + col] = f2h(acc[mi][ni][r]);
            }
        }
}

// ---------------------------------------------------------------------------
// Fused Y/V projection, fp16 MFMA. z=0: Y = NT(Xf, Mt) (scores operand,
// replaces BOTH Q and K projections via scores = X*M*X^T); z=1: V = NT(Xf,
// Wvf), stored transposed Vt[b][d][s]. 128x128 tile, 4 waves x 64x64, BK=64,
// XOR-swizzled LDS (linear gld_lds dest + inverse-swizzled global source +
// swizzled read). 2-D grid, m fastest (keeps 256 KB B-panel L2-hot).
// ---------------------------------------------------------------------------
__global__ __launch_bounds__(256) void yv_gemm(
    const unsigned short* __restrict__ Xf, const unsigned short* __restrict__ Mt,
    const unsigned short* __restrict__ Wvf,
    unsigned short* __restrict__ Yf, unsigned short* __restrict__ Vt)
{
    __shared__ __attribute__((aligned(16))) unsigned short Ah[128 * 64];
    __shared__ __attribute__((aligned(16))) unsigned short Bh[128 * 64];
    const int m0 = blockIdx.x * 128, n0 = blockIdx.y * 128, z = blockIdx.z;
    const unsigned short* Wz = z ? Wvf : Mt;
    const int tid = threadIdx.x;
    const int w = tid >> 6, lane = tid & 63, q = lane >> 4, c = lane & 15;
    const int wrow = (w >> 1) * 64, wcol = (w & 1) * 64;
    const int g8 = lane >> 3;                 // row-in-group 0..7
    const int cu = (lane & 7) ^ g8;           // inverse-swizzled col unit
    const int srow = w * 8 + g8;              // staging row (call j adds j*32)
    const int scol = cu * 8;                  // shorts
    unsigned short* lA = Ah + w * 512;        // wave-uniform LDS bases
    unsigned short* lB = Bh + w * 512;
    const int c7 = c & 7;

    f32x4 acc[4][4];
#pragma unroll
    for (int a = 0; a < 4; ++a)
#pragma unroll
        for (int b = 0; b < 4; ++b) acc[a][b] = (f32x4){0.f, 0.f, 0.f, 0.f};

    for (int k0 = 0; k0 < DIM; k0 += 64) {
        __syncthreads();
        {
            const size_t ga = (size_t)(m0 + srow) * DIM + k0 + scol;
            const size_t gb = (size_t)(n0 + srow) * DIM + k0 + scol;
#pragma unroll
            for (int j = 0; j < 4; ++j) {
                gld_lds16(Xf + ga + (size_t)(j * 32) * DIM, lA + j * 2048);
                gld_lds16(Wz + gb + (size_t)(j * 32) * DIM, lB + j * 2048);
            }
        }
        __syncthreads();
#pragma unroll
        for (int kk = 0; kk < 2; ++kk) {
            f16x8 ah[4], bh[4];
#pragma unroll
            for (int mi = 0; mi < 4; ++mi)
                ah[mi] = ldsld(Ah + (wrow + mi * 16 + c) * 64 + (((kk << 2) + q) ^ c7) * 8);
#pragma unroll
            for (int ni = 0; ni < 4; ++ni)
                bh[ni] = ldsld(Bh + (wcol + ni * 16 + c) * 64 + (((kk << 2) + q) ^ c7) * 8);
#pragma unroll
            for (int mi = 0; mi < 4; ++mi)
#pragma unroll
                for (int ni = 0; ni < 4; ++ni)
                    acc[mi][ni] = __builtin_amdgcn_mfma_f32_16x16x32_f16(ah[mi], bh[ni], acc[mi][ni], 0, 0, 0);
        }
    }

    if (z == 1) {
        // V: store transposed Vt[b][d][s], fp16.
#pragma unroll
        for (int mi = 0; mi < 4; ++mi) {
            const int mg = m0 + wrow + mi * 16 + q * 4;
            const int bb = mg >> 11, ss = mg & (SEQ - 1);
#pragma unroll
            for (int ni = 0; ni < 4; ++ni) {
                const int col = n0 + wcol + ni * 16 + c;
                u16x4v v;
                v.x = f2h(acc[mi][ni][0]);
                v.y = f2h(acc[mi][ni][1]);
                v.z = f2h(acc[mi][ni][2]);
                v.w = f2h(acc[mi][ni][3]);
                *(u16x4v*)(Vt + ((size_t)bb * DIM + col) * SEQ + ss) = v;
            }
        }
    } else {
#pragma unroll
        for (int mi = 0; mi < 4; ++mi)
#pragma unroll
            for (int ni = 0; ni < 4; ++ni) {
                const int col = n0 + wcol + ni * 16 + c;
#pragma unroll
                for (int r = 0; r < 4; ++r) {
                    const int row = m0 + wrow + mi * 16 + q * 4 + r;
                    Yf[(size_t)row * DIM + col] = f2h(acc[mi][ni][r]);
                }
            }
    }
}

// ---------------------------------------------------------------------------
// Scores GEMM, ALL batches: S = Yf Xf^T * SCALE (== Q K^T), fp16 out.
// Faithful masking of scores==0 on the f32 accumulator: writes 0xFC00.
// Triangular-flattened grid: x = t in [0,136). BK=64 swizzled.
// ---------------------------------------------------------------------------
__global__ __launch_bounds__(256) void scores_gemm1b(
    const unsigned short* __restrict__ Q, const unsigned short* __restrict__ K,
    unsigned short* __restrict__ S)
{
    __shared__ __attribute__((aligned(16))) unsigned short Ah[128 * 64];
    __shared__ __attribute__((aligned(16))) unsigned short Bh[128 * 64];
    const int t = blockIdx.x;                  // 0..135
    int ti = (int)((__builtin_sqrtf(8.f * t + 1.f) - 1.f) * 0.5f);
    while ((ti + 1) * (ti + 2) / 2 <= t) ++ti;
    while (ti * (ti + 1) / 2 > t) --ti;
    const int tj = t - ti * (ti + 1) / 2;
    const int i0 = ti * 128, j0 = tj * 128, b = blockIdx.z;
    const unsigned short* Qb = Q + (size_t)b * SEQ * DIM;
    const unsigned short* Kb = K + (size_t)b * SEQ * DIM;
    unsigned short* Sb = S + (size_t)b * SEQ * SEQ;
    const int tid = threadIdx.x;
    const int w = tid >> 6, lane = tid & 63, q = lane >> 4, c = lane & 15;
    const int wrow = (w >> 1) * 64, wcol = (w & 1) * 64;
    const int g8 = lane >> 3;
    const int cu = (lane & 7) ^ g8;
    const int srow = w * 8 + g8;
    const int scol = cu * 8;
    unsigned short* lA = Ah + w * 512;
    unsigned short* lB = Bh + w * 512;
    const int c7 = c & 7;

    f32x4 acc[4][4];
#pragma unroll
    for (int a = 0; a < 4; ++a)
#pragma unroll
        for (int bq = 0; bq < 4; ++bq) acc[a][bq] = (f32x4){0.f, 0.f, 0.f, 0.f};

    for (int k0 = 0; k0 < DIM; k0 += 64) {
        __syncthreads();
        {
            const size_t ga = (size_t)(i0 + srow) * DIM + k0 + scol;
            const size_t gb = (size_t)(j0 + srow) * DIM + k0 + scol;
#pragma unroll
            for (int j = 0; j < 4; ++j) {
                gld_lds16(Qb + ga + (size_t)(j * 32) * DIM, lA + j * 2048);
                gld_lds16(Kb + gb + (size_t)(j * 32) * DIM, lB + j * 2048);
            }
        }
        __syncthreads();
#pragma unroll
        for (int kk = 0; kk < 2; ++kk) {
            f16x8 ah[4], bh[4];
#pragma unroll
            for (int mi = 0; mi < 4; ++mi)
                ah[mi] = ldsld(Ah + (wrow + mi * 16 + c) * 64 + (((kk << 2) + q) ^ c7) * 8);
#pragma unroll
            for (int ni = 0; ni < 4; ++ni)
                bh[ni] = ldsld(Bh + (wcol + ni * 16 + c) * 64 + (((kk << 2) + q) ^ c7) * 8);
#pragma unroll
            for (int mi = 0; mi < 4; ++mi)
#pragma unroll
                for (int ni = 0; ni < 4; ++ni)
                    acc[mi][ni] = __builtin_amdgcn_mfma_f32_16x16x32_f16(ah[mi], bh[ni], acc[mi][ni], 0, 0, 0);
        }
    }
#pragma unroll
    for (int mi = 0; mi < 4; ++mi)
#pragma unroll
        for (int ni = 0; ni < 4; ++ni) {
            const int col = j0 + wcol + ni * 16 + c;
#pragma unroll
            for (int r = 0; r < 4; ++r) {
                const int row = i0 + wrow + mi * 16 + q * 4 + r;
                const float sc = acc[mi][ni][r] * 0.03125f;
                Sb[(size_t)row * SEQ + col] =
                    (sc == 0.f) ? (unsigned short)0xFC00u : f2h(sc);
            }
        }
}

// ---------------------------------------------------------------------------
// Row-wise masked softmax: fp16 S -> fp16 P. j > i masked; scores==0 already
// -inf. Skip loads beyond i, skip writes beyond rowtile end. Grid (SEQ, BATCH).
// ---------------------------------------------------------------------------
__global__ __launch_bounds__(256) void softmax_row_b(
    const unsigned short* __restrict__ S, unsigned short* __restrict__ P)
{
    const int i = blockIdx.x, t = threadIdx.x;
    const size_t ro = ((size_t)blockIdx.y * SEQ + i) * SEQ;
    const int wid = t >> 6, lane = t & 63;
    __shared__ float redm[4], reds[4];
    const int j0 = t * 8;
    const int rti = (i & ~127) + 128;        // pv reads cols < rti only
    float sv[8];
    float mx = -__builtin_inff();
    if (j0 <= i) {
        u16x8v raw = *(const u16x8v*)(S + ro + j0);
#pragma unroll
        for (int u = 0; u < 8; ++u) {
            float s = (j0 + u <= i) ? h2f(raw[u]) : -__builtin_inff();
            sv[u] = s;
            mx = fmaxf(mx, s);
        }
    } else {
#pragma unroll
        for (int u = 0; u < 8; ++u) sv[u] = -__builtin_inff();
    }
#pragma unroll
    for (int off = 1; off < 64; off <<= 1) mx = fmaxf(mx, __shfl_xor(mx, off));
    if (lane == 0) redm[wid] = mx;
    __syncthreads();
    const float M = fmaxf(fmaxf(redm[0], redm[1]), fmaxf(redm[2], redm[3]));
    float sum = 0.f;
#pragma unroll
    for (int u = 0; u < 8; ++u) {
        float e = __expf(sv[u] - M);
        sv[u] = e;
        sum += e;
    }
#pragma unroll
    for (int off = 1; off < 64; off <<= 1) sum += __shfl_xor(sum, off);
    if (lane == 0) reds[wid] = sum;
    __syncthreads();
    const float rinv = 1.f / (reds[0] + reds[1] + reds[2] + reds[3]);
    if (j0 < rti) {
        u16x8v o;
#pragma unroll
        for (int u = 0; u < 8; ++u) o[u] = f2h(sv[u] * rinv);
        *(u16x8v*)(P + ro + j0) = o;
    }
}

// ---------------------------------------------------------------------------
// out = P @ V via Vt (NT MFMA, fp16), fp32 store. 128x128 tile, BK=64
// swizzled; k-loop truncated at causal bound. Long/short tiles interleaved
// across batch halves.
// ---------------------------------------------------------------------------
__global__ __launch_bounds__(256) void pv_gemm(
    const unsigned short* __restrict__ Pm, const unsigned short* __restrict__ Vt,
    float* __restrict__ Out)
{
    __shared__ __attribute__((aligned(16))) unsigned short Ps[128 * 64];
    __shared__ __attribute__((aligned(16))) unsigned short Vs[128 * 64];
    const int b = blockIdx.z;
    const int i0t = (b < 2) ? blockIdx.x : 15 - blockIdx.x;
    const int i0 = i0t * 128, d0 = blockIdx.y * 128;
    const int tid = threadIdx.x;
    const int w = tid >> 6, lane = tid & 63, q = lane >> 4, c = lane & 15;
    const int wrow = (w >> 1) * 64, wcol = (w & 1) * 64;
    const int g8 = lane >> 3;
    const int cu = (lane & 7) ^ g8;
    const int srow = w * 8 + g8;
    const int scol = cu * 8;
    unsigned short* lA = Ps + w * 512;
    unsigned short* lB = Vs + w * 512;
    const int c7 = c & 7;

    f32x4 acc[4][4];
#pragma unroll
    for (int a = 0; a < 4; ++a)
#pragma unroll
        for (int bq = 0; bq < 4; ++bq) acc[a][bq] = (f32x4){0.f, 0.f, 0.f, 0.f};

    const int njs = 2 * i0t + 2;  // covers cols < i0+128

    for (int ks = 0; ks < njs; ++ks) {
        const int j0 = ks * 64;
        __syncthreads();
        {
            const size_t gpa = ((size_t)b * SEQ + i0 + srow) * SEQ + j0 + scol;
            const size_t gva = ((size_t)b * DIM + d0 + srow) * SEQ + j0 + scol;
#pragma unroll
            for (int j = 0; j < 4; ++j) {
                gld_lds16(Pm + gpa + (size_t)(j * 32) * SEQ, lA + j * 2048);
                gld_lds16(Vt + gva + (size_t)(j * 32) * SEQ, lB + j * 2048);
            }
        }
        __syncthreads();
#pragma unroll
        for (int kk = 0; kk < 2; ++kk) {
            f16x8 ah[4], bh[4];
#pragma unroll
            for (int mi = 0; mi < 4; ++mi)
                ah[mi] = ldsld(Ps + (wrow + mi * 16 + c) * 64 + (((kk << 2) + q) ^ c7) * 8);
#pragma unroll
            for (int ni = 0; ni < 4; ++ni)
                bh[ni] = ldsld(Vs + (wcol + ni * 16 + c) * 64 + (((kk << 2) + q) ^ c7) * 8);
#pragma unroll
            for (int mi = 0; mi < 4; ++mi)
#pragma unroll
                for (int ni = 0; ni < 4; ++ni)
                    acc[mi][ni] = __builtin_amdgcn_mfma_f32_16x16x32_f16(ah[mi], bh[ni], acc[mi][ni], 0, 0, 0);
        }
    }
#pragma unroll
    for (int mi = 0; mi < 4; ++mi)
#pragma unroll
        for (int ni = 0; ni < 4; ++ni) {
            const int dcol = d0 + wcol + ni * 16 + c;
#pragma unroll
            for (int r = 0; r < 4; ++r) {
                const int i = i0 + wrow + mi * 16 + q * 4 + r;
                Out[((size_t)b * SEQ + i) * DIM + dcol] = acc[mi][ni][r];
            }
        }
}

extern "C" void kernel_launch(void* const* d_in, const int* in_sizes, int n_in,
                              void* d_out, int out_size, void* d_ws, size_t ws_size,
                              hipStream_t stream)
{
    (void)out_size; (void)ws_size;
    const float* X = nullptr;
    const float* Wv[3] = {nullptr, nullptr, nullptr};
    int nw = 0;
    for (int i = 0; i < n_in; ++i) {
        if (in_sizes[i] == (int)NBS)
            X = (const float*)d_in[i];
        else if (nw < 3)
            Wv[nw++] = (const float*)d_in[i];
    }

    unsigned short* ws = (unsigned short*)d_ws;
    unsigned short* Yf = ws;                 // 16 MB
    unsigned short* Vt = ws + 2 * NBS;       // 16 MB
    unsigned short* Xf = ws + 3 * NBS;       // consumed by yv + scores
    unsigned short* Pp = ws + 3 * NBS;       // P aliases Xf after scores (32 MB)
    unsigned short* Sb = ws + 5 * NBS;       // fp16 S, all batches (32 MB)
    unsigned short* Wf = ws + 7 * NBS;       // 6 MB (Wq,Wk,Wv fp16)
    unsigned short* Mtb = Wf + (size_t)3 * DIM * DIM;  // 2 MB
    float* Out = (float*)d_out;

    // Wv[0]=WQ, Wv[1]=WK, Wv[2]=WV (input order).
    cvt_all<<<dim3(8192 + 3072), 256, 0, stream>>>(X, Wv[0], Wv[1], Wv[2], Xf, Wf);

    mt_gemm<<<dim3(8, 8), 256, 0, stream>>>(
        Wf, Wf + (size_t)DIM * DIM, Mtb);

    yv_gemm<<<dim3(64, 8, 2), 256, 0, stream>>>(
        Xf, Mtb, Wf + (size_t)2 * DIM * DIM, Yf, Vt);

    scores_gemm1b<<<dim3(136, 1, BATCH), 256, 0, stream>>>(Yf, Xf, Sb);
    softmax_row_b<<<dim3(SEQ, BATCH), 256, 0, stream>>>(Sb, Pp);

    pv_gemm<<<dim3(16, 8, BATCH), 256, 0, stream>>>(Pp, Vt, Out);
}

// Round 8
// 237.180 us; speedup vs baseline: 1.2554x; 1.0926x over previous
//
#include <hip/hip_runtime.h>

typedef _Float16 f16x8 __attribute__((ext_vector_type(8)));
typedef unsigned short u16x8v __attribute__((ext_vector_type(8)));
typedef unsigned short u16x4v __attribute__((ext_vector_type(4)));
typedef float f32x4 __attribute__((ext_vector_type(4)));

constexpr int SEQ = 2048;
constexpr int DIM = 1024;
constexpr int BATCH = 4;
constexpr size_t NBS = (size_t)BATCH * SEQ * DIM;  // 8388608

static __device__ __forceinline__ unsigned short f2h(float f) {
    return __builtin_bit_cast(unsigned short, (_Float16)f);  // RNE
}
static __device__ __forceinline__ float h2f(unsigned short u) {
    return (float)__builtin_bit_cast(_Float16, u);
}
static __device__ __forceinline__ f16x8 ldsld(const unsigned short* p) {
    return __builtin_bit_cast(f16x8, *(const u16x8v*)p);
}
// Async global->LDS, 16B/lane. LDS dest = wave-uniform base + lane*16B.
static __device__ __forceinline__ void gld_lds16(const unsigned short* g, unsigned short* l) {
    __builtin_amdgcn_global_load_lds(
        (const __attribute__((address_space(1))) void*)g,
        (__attribute__((address_space(3))) void*)l, 16, 0, 0);
}

// ---------------------------------------------------------------------------
// cvt + transpose, ONE launch:
//   [0,8192):            X fp32 -> fp16.
//   [8192,8192+3072):    Wq,Wk,Wv fp32 -> fp16 (k-major, as input).
//   [11264,11264+512):   WqT/WkT fp32 -> fp16 TRANSPOSED [e][k] (64x64 LDS
//                        tiles) so mt_gemm can be a standard NT GEMM.
// ---------------------------------------------------------------------------
__global__ __launch_bounds__(256) void cvt_all(
    const float* __restrict__ X,
    const float* __restrict__ W0, const float* __restrict__ W1,
    const float* __restrict__ W2,
    unsigned short* __restrict__ Xf, unsigned short* __restrict__ Wf,
    unsigned short* __restrict__ WqT, unsigned short* __restrict__ WkT)
{
    __shared__ __attribute__((aligned(16))) unsigned short T[64][72];  // 144B rows: 16B-aligned
    const int b = blockIdx.x;
    const int t = threadIdx.x;
    if (b < 11264) {
        const float* src;
        unsigned short* dst;
        int i;
        if (b < 8192) {
            src = X; dst = Xf;
            i = b * 256 + t;
        } else {
            const int wb = b - 8192;
            const int z = wb >> 10;              // 1024 blocks per weight
            src = (z == 0) ? W0 : (z == 1) ? W1 : W2;
            dst = Wf + (size_t)z * DIM * DIM;
            i = (wb & 1023) * 256 + t;
        }
        float4 f = ((const float4*)src)[i];
        u16x4v h;
        h.x = f2h(f.x); h.y = f2h(f.y); h.z = f2h(f.z); h.w = f2h(f.w);
        ((u16x4v*)dst)[i] = h;
        return;
    }
    // ---- transpose blocks ----
    const int tb = b - 11264;                    // 0..511
    const float* src = (tb < 256) ? W0 : W1;     // Wq then Wk
    unsigned short* dst = (tb < 256) ? WqT : WkT;
    const int tile = tb & 255;
    const int tk = (tile >> 4) * 64;             // k tile base
    const int te = (tile & 15) * 64;             // e tile base
    const int cu = t & 15, kr4 = t >> 4;         // read: 16 rows/pass, 4 cols/thread
#pragma unroll
    for (int p = 0; p < 4; ++p) {
        const int k = p * 16 + kr4;
        float4 v = *(const float4*)(src + (size_t)(tk + k) * DIM + te + cu * 4);
        T[cu * 4 + 0][k] = f2h(v.x);
        T[cu * 4 + 1][k] = f2h(v.y);
        T[cu * 4 + 2][k] = f2h(v.z);
        T[cu * 4 + 3][k] = f2h(v.w);
    }
    __syncthreads();
    const int un = t & 7, er = t >> 3;           // write: 32 rows/pass, 16B/thread
#pragma unroll
    for (int p = 0; p < 2; ++p) {
        const int e = p * 32 + er;
        *(u16x8v*)(dst + (size_t)(te + e) * DIM + tk + un * 8) =
            *(const u16x8v*)&T[e][un * 8];
    }
}

// ---------------------------------------------------------------------------
// Mt[e'][e] = sum_k Wk[k][e'] Wq[k][e] as a standard NT GEMM on the
// TRANSPOSED copies: A = WkT [e'][k], B = WqT [e][k]. Same swizzled BK=64
// structure as yv_gemm. Grid (8,8), ~6 us. (r7's fragment-time scalar
// transpose was ~25-30 us serial -- replaced.)
// ---------------------------------------------------------------------------
__global__ __launch_bounds__(256) void mt_gemm(
    const unsigned short* __restrict__ WkTp, const unsigned short* __restrict__ WqTp,
    unsigned short* __restrict__ Mt)
{
    __shared__ __attribute__((aligned(16))) unsigned short Ah[128 * 64];
    __shared__ __attribute__((aligned(16))) unsigned short Bh[128 * 64];
    const int m0 = blockIdx.x * 128, n0 = blockIdx.y * 128;  // e' rows, e cols
    const int tid = threadIdx.x;
    const int w = tid >> 6, lane = tid & 63, q = lane >> 4, c = lane & 15;
    const int wrow = (w >> 1) * 64, wcol = (w & 1) * 64;
    const int g8 = lane >> 3;
    const int cu = (lane & 7) ^ g8;
    const int srow = w * 8 + g8;
    const int scol = cu * 8;
    unsigned short* lA = Ah + w * 512;
    unsigned short* lB = Bh + w * 512;
    const int c7 = c & 7;

    f32x4 acc[4][4];
#pragma unroll
    for (int a = 0; a < 4; ++a)
#pragma unroll
        for (int bq = 0; bq < 4; ++bq) acc[a][bq] = (f32x4){0.f, 0.f, 0.f, 0.f};

    for (int k0 = 0; k0 < DIM; k0 += 64) {
        __syncthreads();
        {
            const size_t ga = (size_t)(m0 + srow) * DIM + k0 + scol;
            const size_t gb = (size_t)(n0 + srow) * DIM + k0 + scol;
#pragma unroll
            for (int j = 0; j < 4; ++j) {
                gld_lds16(WkTp + ga + (size_t)(j * 32) * DIM, lA + j * 2048);
                gld_lds16(WqTp + gb + (size_t)(j * 32) * DIM, lB + j * 2048);
            }
        }
        __syncthreads();
#pragma unroll
        for (int kk = 0; kk < 2; ++kk) {
            f16x8 af[4], bf[4];
#pragma unroll
            for (int mi = 0; mi < 4; ++mi)
                af[mi] = ldsld(Ah + (wrow + mi * 16 + c) * 64 + (((kk << 2) + q) ^ c7) * 8);
#pragma unroll
            for (int ni = 0; ni < 4; ++ni)
                bf[ni] = ldsld(Bh + (wcol + ni * 16 + c) * 64 + (((kk << 2) + q) ^ c7) * 8);
#pragma unroll
            for (int mi = 0; mi < 4; ++mi)
#pragma unroll
                for (int ni = 0; ni < 4; ++ni)
                    acc[mi][ni] = __builtin_amdgcn_mfma_f32_16x16x32_f16(af[mi], bf[ni], acc[mi][ni], 0, 0, 0);
        }
    }
#pragma unroll
    for (int mi = 0; mi < 4; ++mi)
#pragma unroll
        for (int ni = 0; ni < 4; ++ni) {
            const int col = n0 + wcol + ni * 16 + c;
#pragma unroll
            for (int r = 0; r < 4; ++r) {
                const int row = m0 + wrow + mi * 16 + q * 4 + r;
                Mt[(size_t)row * DIM + col] = f2h(acc[mi][ni][r]);
            }
        }
}

// ---------------------------------------------------------------------------
// Fused Y/V projection, fp16 MFMA. z=0: Y = NT(Xf, Mt); z=1: V = NT(Xf, Wvf)
// stored transposed Vt[b][d][s]. 128x128 tile, BK=64 swizzled, m fastest.
// ---------------------------------------------------------------------------
__global__ __launch_bounds__(256) void yv_gemm(
    const unsigned short* __restrict__ Xf, const unsigned short* __restrict__ Mt,
    const unsigned short* __restrict__ Wvf,
    unsigned short* __restrict__ Yf, unsigned short* __restrict__ Vt)
{
    __shared__ __attribute__((aligned(16))) unsigned short Ah[128 * 64];
    __shared__ __attribute__((aligned(16))) unsigned short Bh[128 * 64];
    const int m0 = blockIdx.x * 128, n0 = blockIdx.y * 128, z = blockIdx.z;
    const unsigned short* Wz = z ? Wvf : Mt;
    const int tid = threadIdx.x;
    const int w = tid >> 6, lane = tid & 63, q = lane >> 4, c = lane & 15;
    const int wrow = (w >> 1) * 64, wcol = (w & 1) * 64;
    const int g8 = lane >> 3;
    const int cu = (lane & 7) ^ g8;
    const int srow = w * 8 + g8;
    const int scol = cu * 8;
    unsigned short* lA = Ah + w * 512;
    unsigned short* lB = Bh + w * 512;
    const int c7 = c & 7;

    f32x4 acc[4][4];
#pragma unroll
    for (int a = 0; a < 4; ++a)
#pragma unroll
        for (int b = 0; b < 4; ++b) acc[a][b] = (f32x4){0.f, 0.f, 0.f, 0.f};

    for (int k0 = 0; k0 < DIM; k0 += 64) {
        __syncthreads();
        {
            const size_t ga = (size_t)(m0 + srow) * DIM + k0 + scol;
            const size_t gb = (size_t)(n0 + srow) * DIM + k0 + scol;
#pragma unroll
            for (int j = 0; j < 4; ++j) {
                gld_lds16(Xf + ga + (size_t)(j * 32) * DIM, lA + j * 2048);
                gld_lds16(Wz + gb + (size_t)(j * 32) * DIM, lB + j * 2048);
            }
        }
        __syncthreads();
#pragma unroll
        for (int kk = 0; kk < 2; ++kk) {
            f16x8 ah[4], bh[4];
#pragma unroll
            for (int mi = 0; mi < 4; ++mi)
                ah[mi] = ldsld(Ah + (wrow + mi * 16 + c) * 64 + (((kk << 2) + q) ^ c7) * 8);
#pragma unroll
            for (int ni = 0; ni < 4; ++ni)
                bh[ni] = ldsld(Bh + (wcol + ni * 16 + c) * 64 + (((kk << 2) + q) ^ c7) * 8);
#pragma unroll
            for (int mi = 0; mi < 4; ++mi)
#pragma unroll
                for (int ni = 0; ni < 4; ++ni)
                    acc[mi][ni] = __builtin_amdgcn_mfma_f32_16x16x32_f16(ah[mi], bh[ni], acc[mi][ni], 0, 0, 0);
        }
    }

    if (z == 1) {
        // V: store transposed Vt[b][d][s], fp16.
#pragma unroll
        for (int mi = 0; mi < 4; ++mi) {
            const int mg = m0 + wrow + mi * 16 + q * 4;
            const int bb = mg >> 11, ss = mg & (SEQ - 1);
#pragma unroll
            for (int ni = 0; ni < 4; ++ni) {
                const int col = n0 + wcol + ni * 16 + c;
                u16x4v v;
                v.x = f2h(acc[mi][ni][0]);
                v.y = f2h(acc[mi][ni][1]);
                v.z = f2h(acc[mi][ni][2]);
                v.w = f2h(acc[mi][ni][3]);
                *(u16x4v*)(Vt + ((size_t)bb * DIM + col) * SEQ + ss) = v;
            }
        }
    } else {
#pragma unroll
        for (int mi = 0; mi < 4; ++mi)
#pragma unroll
            for (int ni = 0; ni < 4; ++ni) {
                const int col = n0 + wcol + ni * 16 + c;
#pragma unroll
                for (int r = 0; r < 4; ++r) {
                    const int row = m0 + wrow + mi * 16 + q * 4 + r;
                    Yf[(size_t)row * DIM + col] = f2h(acc[mi][ni][r]);
                }
            }
    }
}

// ---------------------------------------------------------------------------
// Scores GEMM: S = Yf Xf^T * SCALE, fp16 out, scores==0 masked to 0xFC00 on
// the f32 accumulator. 1-D grid 544 = 8 XCD chunks x 68: each XCD takes 68
// CONSECUTIVE triangular-t blocks so its co-resident blocks share Y panels
// and sweep <=16 X panels (4 MB = one L2). r7 (scattered): FETCH 103 MB at
// 2.1 blk/CU latency-bound.
// ---------------------------------------------------------------------------
__global__ __launch_bounds__(256) void scores_gemm1b(
    const unsigned short* __restrict__ Q, const unsigned short* __restrict__ K,
    unsigned short* __restrict__ S)
{
    __shared__ __attribute__((aligned(16))) unsigned short Ah[128 * 64];
    __shared__ __attribute__((aligned(16))) unsigned short Bh[128 * 64];
    const int flat = blockIdx.x;               // 0..543
    const int wg = (flat & 7) * 68 + (flat >> 3);  // XCD-chunked, bijective
    const int b = wg / 136;
    const int t = wg - b * 136;                // 0..135 triangular index
    int ti = (int)((__builtin_sqrtf(8.f * t + 1.f) - 1.f) * 0.5f);
    while ((ti + 1) * (ti + 2) / 2 <= t) ++ti;
    while (ti * (ti + 1) / 2 > t) --ti;
    const int tj = t - ti * (ti + 1) / 2;
    const int i0 = ti * 128, j0 = tj * 128;
    const unsigned short* Qb = Q + (size_t)b * SEQ * DIM;
    const unsigned short* Kb = K + (size_t)b * SEQ * DIM;
    unsigned short* Sb = S + (size_t)b * SEQ * SEQ;
    const int tid = threadIdx.x;
    const int w = tid >> 6, lane = tid & 63, q = lane >> 4, c = lane & 15;
    const int wrow = (w >> 1) * 64, wcol = (w & 1) * 64;
    const int g8 = lane >> 3;
    const int cu = (lane & 7) ^ g8;
    const int srow = w * 8 + g8;
    const int scol = cu * 8;
    unsigned short* lA = Ah + w * 512;
    unsigned short* lB = Bh + w * 512;
    const int c7 = c & 7;

    f32x4 acc[4][4];
#pragma unroll
    for (int a = 0; a < 4; ++a)
#pragma unroll
        for (int bq = 0; bq < 4; ++bq) acc[a][bq] = (f32x4){0.f, 0.f, 0.f, 0.f};

    for (int k0 = 0; k0 < DIM; k0 += 64) {
        __syncthreads();
        {
            const size_t ga = (size_t)(i0 + srow) * DIM + k0 + scol;
            const size_t gb = (size_t)(j0 + srow) * DIM + k0 + scol;
#pragma unroll
            for (int j = 0; j < 4; ++j) {
                gld_lds16(Qb + ga + (size_t)(j * 32) * DIM, lA + j * 2048);
                gld_lds16(Kb + gb + (size_t)(j * 32) * DIM, lB + j * 2048);
            }
        }
        __syncthreads();
#pragma unroll
        for (int kk = 0; kk < 2; ++kk) {
            f16x8 ah[4], bh[4];
#pragma unroll
            for (int mi = 0; mi < 4; ++mi)
                ah[mi] = ldsld(Ah + (wrow + mi * 16 + c) * 64 + (((kk << 2) + q) ^ c7) * 8);
#pragma unroll
            for (int ni = 0; ni < 4; ++ni)
                bh[ni] = ldsld(Bh + (wcol + ni * 16 + c) * 64 + (((kk << 2) + q) ^ c7) * 8);
#pragma unroll
            for (int mi = 0; mi < 4; ++mi)
#pragma unroll
                for (int ni = 0; ni < 4; ++ni)
                    acc[mi][ni] = __builtin_amdgcn_mfma_f32_16x16x32_f16(ah[mi], bh[ni], acc[mi][ni], 0, 0, 0);
        }
    }
#pragma unroll
    for (int mi = 0; mi < 4; ++mi)
#pragma unroll
        for (int ni = 0; ni < 4; ++ni) {
            const int col = j0 + wcol + ni * 16 + c;
#pragma unroll
            for (int r = 0; r < 4; ++r) {
                const int row = i0 + wrow + mi * 16 + q * 4 + r;
                const float sc = acc[mi][ni][r] * 0.03125f;
                Sb[(size_t)row * SEQ + col] =
                    (sc == 0.f) ? (unsigned short)0xFC00u : f2h(sc);
            }
        }
}

// ---------------------------------------------------------------------------
// Row-wise masked softmax: fp16 S -> fp16 P. j > i masked; scores==0 already
// -inf. Skip loads beyond i, skip writes beyond rowtile end. Grid (SEQ, BATCH).
// ---------------------------------------------------------------------------
__global__ __launch_bounds__(256) void softmax_row_b(
    const unsigned short* __restrict__ S, unsigned short* __restrict__ P)
{
    const int i = blockIdx.x, t = threadIdx.x;
    const size_t ro = ((size_t)blockIdx.y * SEQ + i) * SEQ;
    const int wid = t >> 6, lane = t & 63;
    __shared__ float redm[4], reds[4];
    const int j0 = t * 8;
    const int rti = (i & ~127) + 128;        // pv reads cols < rti only
    float sv[8];
    float mx = -__builtin_inff();
    if (j0 <= i) {
        u16x8v raw = *(const u16x8v*)(S + ro + j0);
#pragma unroll
        for (int u = 0; u < 8; ++u) {
            float s = (j0 + u <= i) ? h2f(raw[u]) : -__builtin_inff();
            sv[u] = s;
            mx = fmaxf(mx, s);
        }
    } else {
#pragma unroll
        for (int u = 0; u < 8; ++u) sv[u] = -__builtin_inff();
    }
#pragma unroll
    for (int off = 1; off < 64; off <<= 1) mx = fmaxf(mx, __shfl_xor(mx, off));
    if (lane == 0) redm[wid] = mx;
    __syncthreads();
    const float M = fmaxf(fmaxf(redm[0], redm[1]), fmaxf(redm[2], redm[3]));
    float sum = 0.f;
#pragma unroll
    for (int u = 0; u < 8; ++u) {
        float e = __expf(sv[u] - M);
        sv[u] = e;
        sum += e;
    }
#pragma unroll
    for (int off = 1; off < 64; off <<= 1) sum += __shfl_xor(sum, off);
    if (lane == 0) reds[wid] = sum;
    __syncthreads();
    const float rinv = 1.f / (reds[0] + reds[1] + reds[2] + reds[3]);
    if (j0 < rti) {
        u16x8v o;
#pragma unroll
        for (int u = 0; u < 8; ++u) o[u] = f2h(sv[u] * rinv);
        *(u16x8v*)(P + ro + j0) = o;
    }
}

// ---------------------------------------------------------------------------
// out = P @ V via Vt (NT MFMA, fp16), fp32 store. 128x128 tile, BK=64
// swizzled; k-loop truncated at causal bound. Long/short tiles interleaved
// across batch halves.
// ---------------------------------------------------------------------------
__global__ __launch_bounds__(256) void pv_gemm(
    const unsigned short* __restrict__ Pm, const unsigned short* __restrict__ Vt,
    float* __restrict__ Out)
{
    __shared__ __attribute__((aligned(16))) unsigned short Ps[128 * 64];
    __shared__ __attribute__((aligned(16))) unsigned short Vs[128 * 64];
    const int b = blockIdx.z;
    const int i0t = (b < 2) ? blockIdx.x : 15 - blockIdx.x;
    const int i0 = i0t * 128, d0 = blockIdx.y * 128;
    const int tid = threadIdx.x;
    const int w = tid >> 6, lane = tid & 63, q = lane >> 4, c = lane & 15;
    const int wrow = (w >> 1) * 64, wcol = (w & 1) * 64;
    const int g8 = lane >> 3;
    const int cu = (lane & 7) ^ g8;
    const int srow = w * 8 + g8;
    const int scol = cu * 8;
    unsigned short* lA = Ps + w * 512;
    unsigned short* lB = Vs + w * 512;
    const int c7 = c & 7;

    f32x4 acc[4][4];
#pragma unroll
    for (int a = 0; a < 4; ++a)
#pragma unroll
        for (int bq = 0; bq < 4; ++bq) acc[a][bq] = (f32x4){0.f, 0.f, 0.f, 0.f};

    const int njs = 2 * i0t + 2;  // covers cols < i0+128

    for (int ks = 0; ks < njs; ++ks) {
        const int j0 = ks * 64;
        __syncthreads();
        {
            const size_t gpa = ((size_t)b * SEQ + i0 + srow) * SEQ + j0 + scol;
            const size_t gva = ((size_t)b * DIM + d0 + srow) * SEQ + j0 + scol;
#pragma unroll
            for (int j = 0; j < 4; ++j) {
                gld_lds16(Pm + gpa + (size_t)(j * 32) * SEQ, lA + j * 2048);
                gld_lds16(Vt + gva + (size_t)(j * 32) * SEQ, lB + j * 2048);
            }
        }
        __syncthreads();
#pragma unroll
        for (int kk = 0; kk < 2; ++kk) {
            f16x8 ah[4], bh[4];
#pragma unroll
            for (int mi = 0; mi < 4; ++mi)
                ah[mi] = ldsld(Ps + (wrow + mi * 16 + c) * 64 + (((kk << 2) + q) ^ c7) * 8);
#pragma unroll
            for (int ni = 0; ni < 4; ++ni)
                bh[ni] = ldsld(Vs + (wcol + ni * 16 + c) * 64 + (((kk << 2) + q) ^ c7) * 8);
#pragma unroll
            for (int mi = 0; mi < 4; ++mi)
#pragma unroll
                for (int ni = 0; ni < 4; ++ni)
                    acc[mi][ni] = __builtin_amdgcn_mfma_f32_16x16x32_f16(ah[mi], bh[ni], acc[mi][ni], 0, 0, 0);
        }
    }
#pragma unroll
    for (int mi = 0; mi < 4; ++mi)
#pragma unroll
        for (int ni = 0; ni < 4; ++ni) {
            const int dcol = d0 + wcol + ni * 16 + c;
#pragma unroll
            for (int r = 0; r < 4; ++r) {
                const int i = i0 + wrow + mi * 16 + q * 4 + r;
                Out[((size_t)b * SEQ + i) * DIM + dcol] = acc[mi][ni][r];
            }
        }
}

extern "C" void kernel_launch(void* const* d_in, const int* in_sizes, int n_in,
                              void* d_out, int out_size, void* d_ws, size_t ws_size,
                              hipStream_t stream)
{
    (void)out_size; (void)ws_size;
    const float* X = nullptr;
    const float* Wv[3] = {nullptr, nullptr, nullptr};
    int nw = 0;
    for (int i = 0; i < n_in; ++i) {
        if (in_sizes[i] == (int)NBS)
            X = (const float*)d_in[i];
        else if (nw < 3)
            Wv[nw++] = (const float*)d_in[i];
    }

    unsigned short* ws = (unsigned short*)d_ws;
    unsigned short* Yf = ws;                 // 16 MB
    unsigned short* Vt = ws + 2 * NBS;       // 16 MB
    unsigned short* Xf = ws + 3 * NBS;       // consumed by yv + scores
    unsigned short* Pp = ws + 3 * NBS;       // P aliases Xf after scores (32 MB)
    unsigned short* Sb = ws + 5 * NBS;       // fp16 S, all batches (32 MB)
    unsigned short* Wf = ws + 7 * NBS;       // 6 MB (Wq,Wk,Wv fp16)
    unsigned short* Mtb = Wf + (size_t)3 * DIM * DIM;   // 2 MB
    unsigned short* WqT = Mtb + (size_t)DIM * DIM;      // 2 MB
    unsigned short* WkT = WqT + (size_t)DIM * DIM;      // 2 MB
    float* Out = (float*)d_out;

    // Wv[0]=WQ, Wv[1]=WK, Wv[2]=WV (input order).
    cvt_all<<<dim3(8192 + 3072 + 512), 256, 0, stream>>>(
        X, Wv[0], Wv[1], Wv[2], Xf, Wf, WqT, WkT);

    mt_gemm<<<dim3(8, 8), 256, 0, stream>>>(WkT, WqT, Mtb);

    yv_gemm<<<dim3(64, 8, 2), 256, 0, stream>>>(
        Xf, Mtb, Wf + (size_t)2 * DIM * DIM, Yf, Vt);

    scores_gemm1b<<<dim3(544), 256, 0, stream>>>(Yf, Xf, Sb);
    softmax_row_b<<<dim3(SEQ, BATCH), 256, 0, stream>>>(Sb, Pp);

    pv_gemm<<<dim3(16, 8, BATCH), 256, 0, stream>>>(Pp, Vt, Out);
}